// Round 5
// baseline (226.979 us; speedup 1.0000x reference)
//
#include <hip/hip_runtime.h>
#include <hip/hip_bf16.h>

// HT layer via bf16 MFMA (32x32x16 both stages), one wave per batch element,
// 4 waves (batches) per block, wave-private LDS T slices, no barriers.
//   Y[b] = sum_p A_p(64x64) @ X_b(64x64) @ W_p(64x64) + bias
// Stage A: T^T[kl][ac] = sum_ij X^T[kl][ij] * A_p^T[ij][ac]  (M=kl,N=ac,K=ij)
// Stage B: Y[ac][de]  += sum_kl T[ac][kl]  * W_p[kl][de]     (M=ac,N=de,K=kl)
// mfma_f32_32x32x16_bf16 layouts:
//   A: A[m=lane&31][k=(lane>>5)*8+j]   B: B[k=(lane>>5)*8+j][n=lane&31]
//   C/D: col=lane&31, row=(reg&3)+8*(reg>>2)+4*(lane>>5)   (m74/m101-verified)
// LDS pitch 68 bf16 (136 B): uint2 writes -> 2 lanes/even-bank (optimal);
// b64 reads -> 2-way aliasing = free (m136). 136B rows forbid b128 (8B-align only).
// Round-4 lesson: NO software pipelining across the LDS buffer — aliasing
// WAR forces compiler lgkmcnt(0) serialization. Keep stages serial per p.

typedef short  bf16x8 __attribute__((ext_vector_type(8)));
typedef float  f32x16 __attribute__((ext_vector_type(16)));

union Frag8 {
    bf16x8 v;
    unsigned int u4[4];
    uint2 u2[2];
};

static __device__ __forceinline__ unsigned int pkbf(float a, float b) {
    // v_cvt_pk_bf16_f32 (RNE): a -> low 16, b -> high 16
    __hip_bfloat162 h = __float22bfloat162_rn(float2{a, b});
    return *reinterpret_cast<unsigned int*>(&h);
}

static __device__ __forceinline__ unsigned short f2bf(float f) {
    unsigned int u = __float_as_uint(f);
    u = (u + 0x7FFFu + ((u >> 16) & 1u)) >> 16;   // RNE (precompute only)
    return (unsigned short)u;
}

// Precompute bf16 B-operand (32x32x16) fragments of A_p^T and W_p into ws.
// Layout: frags[isW][p(8)][f=nb*4+kk (8)][lane(64)][j(8)] bf16, 64KB each.
// Element: B[k = kk*16 + (lane>>5)*8 + j][n = nb*32 + (lane&31)]
__global__ void ht_precompute(const float* __restrict__ F0, const float* __restrict__ F1,
                              const float* __restrict__ F2, const float* __restrict__ F3,
                              const float* __restrict__ CL, const float* __restrict__ CR,
                              unsigned short* __restrict__ frags) {
    int idx = blockIdx.x * blockDim.x + threadIdx.x;   // 0..65535
    int isW = idx >> 15;
    int p    = (idx >> 12) & 7;
    int f    = (idx >> 9) & 7;
    int lane = (idx >> 3) & 63;
    int j    = idx & 7;
    int nb = f >> 2, kk = f & 3;
    int n = nb * 32 + (lane & 31);                 // ac or de
    int k = kk * 16 + ((lane >> 5) & 1) * 8 + j;   // ij or kl
    const float* Fa = isW ? F2 : F0;
    const float* Fb = isW ? F3 : F1;
    const float* C  = isW ? CR : CL;
    int i1 = k >> 3, i2 = k & 7, o1 = n >> 3, o2 = n & 7;
    float acc = 0.f;
    for (int r = 0; r < 8; ++r) {
        float fa = Fa[(i1 * 8 + o1) * 8 + r];
        for (int s = 0; s < 8; ++s)
            acc += fa * Fb[(i2 * 8 + o2) * 8 + s] * C[(r * 8 + s) * 8 + p];
    }
    frags[(size_t)isW * 32768 + ((p * 8 + f) << 9) + lane * 8 + j] = f2bf(acc);
}

#define T_PITCH 68   // bf16/row; 136 B: write optimal, b64 read 2-way (free)

__global__ __launch_bounds__(256, 4) void ht_main(const float* __restrict__ x,
                                                  const unsigned short* __restrict__ frags,
                                                  const float* __restrict__ bias,
                                                  float* __restrict__ out) {
    __shared__ unsigned short Tl[4 * 64 * T_PITCH];   // 34.8 KB, one slice per wave
    const int tid  = threadIdx.x;
    const int lane = tid & 63;
    const int w    = __builtin_amdgcn_readfirstlane(tid >> 6);
    const int b    = blockIdx.x * 4 + w;
    unsigned short* Tw = Tl + w * (64 * T_PITCH);

    const int l31 = lane & 31;
    const int h   = (lane >> 5) & 1;   // half

    // X^T A-frags (32x32x16): xf[mb][kk] elem j = X^T[kl=mb*32+l31][ij=kk*16+h*8+j]
    //                                           = x[b][(kk*16+h*8+j)*64 + mb*32+l31]
    Frag8 xf[2][4];
    const float* xb = x + ((size_t)b << 12);
#pragma unroll
    for (int mb = 0; mb < 2; ++mb)
#pragma unroll
        for (int kk = 0; kk < 4; ++kk) {
            const float* src = xb + (kk * 16 + h * 8) * 64 + mb * 32 + l31;
#pragma unroll
            for (int j = 0; j < 8; j += 2)
                xf[mb][kk].u4[j >> 1] = pkbf(src[j * 64], src[(j + 1) * 64]);
        }

    f32x16 acc[2][2];   // Y tiles: [rb over ac][nb over de]
#pragma unroll
    for (int i = 0; i < 2; ++i)
#pragma unroll
        for (int j = 0; j < 2; ++j)
#pragma unroll
            for (int e = 0; e < 16; ++e)
                acc[i][j][e] = 0.f;

    const unsigned short* AF = frags;          // A^T frags
    const unsigned short* WF = frags + 32768;  // W frags

#pragma unroll 1
    for (int p = 0; p < 8; ++p) {
        // ---- Stage A: T^T = X^T @ A_p^T -> bf16 tiles in Tw[ac][kl]
#pragma unroll
        for (int nb = 0; nb < 2; ++nb) {       // nb: ac col-block
            Frag8 af[4];
#pragma unroll
            for (int kk = 0; kk < 4; ++kk)
                af[kk].v = *(const bf16x8*)(AF + (((p * 8 + nb * 4 + kk) << 9) + lane * 8));
#pragma unroll
            for (int mb = 0; mb < 2; ++mb) {   // mb: kl row-block
                f32x16 t;
#pragma unroll
                for (int e = 0; e < 16; ++e) t[e] = 0.f;
#pragma unroll
                for (int kk = 0; kk < 4; ++kk)
                    t = __builtin_amdgcn_mfma_f32_32x32x16_bf16(xf[mb][kk].v, af[kk].v, t, 0, 0, 0);
                // lane: col ac = nb*32+l31; reg r: row kl = mb*32 + (r&3)+8*(r>>2)+4*h
#pragma unroll
                for (int g = 0; g < 4; ++g) {
                    uint2 wv;
                    wv.x = pkbf(t[4 * g + 0], t[4 * g + 1]);
                    wv.y = pkbf(t[4 * g + 2], t[4 * g + 3]);
                    *(uint2*)(&Tw[(nb * 32 + l31) * T_PITCH + mb * 32 + 8 * g + 4 * h]) = wv;
                }
            }
        }
        // ---- Stage B: Y += T @ W_p (same-wave LDS RAW; compiler inserts lgkmcnt)
#pragma unroll
        for (int nb = 0; nb < 2; ++nb) {       // nb: de col-block
            Frag8 wfr[4];
#pragma unroll
            for (int kk = 0; kk < 4; ++kk)
                wfr[kk].v = *(const bf16x8*)(WF + (((p * 8 + nb * 4 + kk) << 9) + lane * 8));
#pragma unroll
            for (int rb = 0; rb < 2; ++rb) {   // rb: ac row-block
                Frag8 tf[4];   // A-frag: T[ac=rb*32+l31][kl=kk*16+h*8+j]
#pragma unroll
                for (int kk = 0; kk < 4; ++kk) {
                    const unsigned short* src = &Tw[(rb * 32 + l31) * T_PITCH + kk * 16 + h * 8];
                    tf[kk].u2[0] = *(const uint2*)(src);
                    tf[kk].u2[1] = *(const uint2*)(src + 4);
                }
#pragma unroll
                for (int kk = 0; kk < 4; ++kk)
                    acc[rb][nb] = __builtin_amdgcn_mfma_f32_32x32x16_bf16(tf[kk].v, wfr[kk].v, acc[rb][nb], 0, 0, 0);
            }
        }
    }

    // ---- Epilogue: bias + store
    // C/D: col de = nb*32+l31; reg r: row ac = rb*32 + (r&3)+8*(r>>2)+4*h
    float* ob = out + ((size_t)b << 12);
#pragma unroll
    for (int rb = 0; rb < 2; ++rb)
#pragma unroll
        for (int nb = 0; nb < 2; ++nb) {
            int de = nb * 32 + l31;
#pragma unroll
            for (int g = 0; g < 4; ++g)
#pragma unroll
                for (int r = 0; r < 4; ++r) {
                    int ac = rb * 32 + 8 * g + 4 * h + r;
                    int o  = ac * 64 + de;
                    ob[o] = acc[rb][nb][4 * g + r] + bias[o];
                }
        }
}

extern "C" void kernel_launch(void* const* d_in, const int* in_sizes, int n_in,
                              void* d_out, int out_size, void* d_ws, size_t ws_size,
                              hipStream_t stream) {
    const float* x    = (const float*)d_in[0];
    const float* F0   = (const float*)d_in[1];
    const float* F1   = (const float*)d_in[2];
    const float* F2   = (const float*)d_in[3];
    const float* F3   = (const float*)d_in[4];
    const float* CL   = (const float*)d_in[5];
    const float* CR   = (const float*)d_in[6];
    const float* bias = (const float*)d_in[7];
    float* out = (float*)d_out;
    unsigned short* frags = (unsigned short*)d_ws;   // 128 KB

    const int B = in_sizes[0] / 4096;   // 4096

    ht_precompute<<<256, 256, 0, stream>>>(F0, F1, F2, F3, CL, CR, frags);
    ht_main<<<B / 4, 256, 0, stream>>>(x, frags, bias, out);
}